// Round 2
// baseline (211.719 us; speedup 1.0000x reference)
//
#include <hip/hip_runtime.h>
#include <hip/hip_bf16.h>

typedef __attribute__((ext_vector_type(4))) float  f32x4;
typedef __attribute__((ext_vector_type(4))) float  float4v;
typedef __attribute__((ext_vector_type(8))) short  bf16x8;
typedef __attribute__((ext_vector_type(4))) short  bf16x4;

#define LDT     72      // padded LDS row stride (bf16 units) = 144 B
#define XSTR_B  65536   // 32*32*64
#define XSTR_H  2048    // 32*64
#define XSTR_W  64
#define WSTR_P  36864   // 576*64
#define OSTR_B  57600   // 30*30*64

__device__ __forceinline__ short f2bf(float f) {
  union { float f; unsigned u; } v; v.f = f;
  unsigned r = v.u + 0x7fffu + ((v.u >> 16) & 1u);  // RNE
  return (short)(r >> 16);
}

__global__ __launch_bounds__(256, 4)
void lc2d_kernel(const float* __restrict__ x, const float* __restrict__ wgt,
                 const float* __restrict__ bias, float* __restrict__ out) {
  __shared__ short Asm[64 * LDT];   // A[b][k]  (patches, bf16)
  __shared__ short Wsm[64 * LDT];   // W^T[o][k] (weights, bf16)

  // bijective XCD swizzle: nwg=900, 8 XCDs, q=112, rr=4
  int orig = blockIdx.x;
  int xcd  = orig & 7;
  int idx  = orig >> 3;
  int p = (xcd < 4 ? xcd * 113 : 4 * 113 + (xcd - 4) * 112) + idx;
  int r = p / 30;
  int c = p - r * 30;

  int tid  = threadIdx.x;
  int lane = tid & 63;
  int wid  = tid >> 6;
  int wr   = (wid >> 1) * 32;   // wave's batch-row offset
  int wc   = (wid & 1) * 32;    // wave's filter-col offset
  int l16  = lane & 15;
  int lhi  = lane >> 4;

  // A staging coords: thread owns float4 at (row = it*16 + tid>>4, k = ac4..ac4+3)
  int ac4   = (tid & 15) * 4;
  int arow0 = tid >> 4;

  const float* xbase = x + (r * XSTR_H + c * XSTR_W);
  const float* wbase = wgt + p * WSTR_P;

  float4v av[4];
  float   wv[16];

  f32x4 acc[2][2] = {{{0.f,0.f,0.f,0.f},{0.f,0.f,0.f,0.f}},
                     {{0.f,0.f,0.f,0.f},{0.f,0.f,0.f,0.f}}};

  // chunk t covers f = t*64 .. t*64+63 ; di = t/3, dj = t%3 (compile-time after unroll)
  auto issue_loads = [&](int t) {
    int di = t / 3, dj = t - di * 3;
    const float* xa = xbase + di * XSTR_H + dj * XSTR_W + ac4;
#pragma unroll
    for (int it = 0; it < 4; ++it) {
      int b = it * 16 + arow0;
      av[it] = *(const float4v*)(xa + (long)b * XSTR_B);
    }
    // W: each wave reads 16 full f-rows, one row per load instr (lane = o, 256B contiguous)
    const float* wa = wbase + (t * 64 + wid * 16) * 64 + lane;
#pragma unroll
    for (int i = 0; i < 16; ++i) wv[i] = wa[i * 64];
  };

  issue_loads(0);

#pragma unroll
  for (int t = 0; t < 9; ++t) {
    __syncthreads();                 // previous chunk's LDS reads done
    // ---- stage A: bf16x4 writes, row b, cols ac4..ac4+3
#pragma unroll
    for (int it = 0; it < 4; ++it) {
      int b = it * 16 + arow0;
      bf16x4 w4 = { f2bf(av[it].x), f2bf(av[it].y), f2bf(av[it].z), f2bf(av[it].w) };
      *(bf16x4*)&Asm[b * LDT + ac4] = w4;
    }
    // ---- stage W transposed: lane holds W[f = t*64+wid*16+i][o = lane] -> Wsm[o][k]
    {
      bf16x8 lo, hi;
#pragma unroll
      for (int i = 0; i < 8; ++i) { lo[i] = f2bf(wv[i]); hi[i] = f2bf(wv[8 + i]); }
      *(bf16x8*)&Wsm[lane * LDT + wid * 16]     = lo;
      *(bf16x8*)&Wsm[lane * LDT + wid * 16 + 8] = hi;
    }
    __syncthreads();
    if (t < 8) issue_loads(t + 1);   // prefetch next chunk; overlaps MFMAs below
    // ---- compute: 2 k-steps of 32, 2x2 fragments
#pragma unroll
    for (int s = 0; s < 2; ++s) {
      int kb = s * 32 + lhi * 8;
      bf16x8 a0 = *(const bf16x8*)&Asm[(wr +  0 + l16) * LDT + kb];
      bf16x8 a1 = *(const bf16x8*)&Asm[(wr + 16 + l16) * LDT + kb];
      bf16x8 b0 = *(const bf16x8*)&Wsm[(wc +  0 + l16) * LDT + kb];
      bf16x8 b1 = *(const bf16x8*)&Wsm[(wc + 16 + l16) * LDT + kb];
      acc[0][0] = __builtin_amdgcn_mfma_f32_16x16x32_bf16(a0, b0, acc[0][0], 0, 0, 0);
      acc[0][1] = __builtin_amdgcn_mfma_f32_16x16x32_bf16(a0, b1, acc[0][1], 0, 0, 0);
      acc[1][0] = __builtin_amdgcn_mfma_f32_16x16x32_bf16(a1, b0, acc[1][0], 0, 0, 0);
      acc[1][1] = __builtin_amdgcn_mfma_f32_16x16x32_bf16(a1, b1, acc[1][1], 0, 0, 0);
    }
  }

  // ---- epilogue: bias + relu + store (D layout: col = lane&15, row = (lane>>4)*4 + reg)
  const float* bb = bias + (r * 30 + c) * 64;
  float bv0 = bb[wc + l16];
  float bv1 = bb[wc + 16 + l16];
  float* ob = out + (r * 30 + c) * 64;
#pragma unroll
  for (int m = 0; m < 2; ++m) {
#pragma unroll
    for (int j = 0; j < 4; ++j) {
      int b = wr + m * 16 + lhi * 4 + j;
#pragma unroll
      for (int n = 0; n < 2; ++n) {
        float v = acc[m][n][j] + (n ? bv1 : bv0);
        ob[(long)b * OSTR_B + wc + n * 16 + l16] = fmaxf(v, 0.f);
      }
    }
  }
}

extern "C" void kernel_launch(void* const* d_in, const int* in_sizes, int n_in,
                              void* d_out, int out_size, void* d_ws, size_t ws_size,
                              hipStream_t stream) {
  const float* x    = (const float*)d_in[0];
  const float* wgt  = (const float*)d_in[1];
  const float* bias = (const float*)d_in[2];
  float* out = (float*)d_out;
  hipLaunchKernelGGL(lc2d_kernel, dim3(900), dim3(256), 0, stream, x, wgt, bias, out);
}

// Round 4
// 204.361 us; speedup vs baseline: 1.0360x; 1.0360x over previous
//
#include <hip/hip_runtime.h>
#include <hip/hip_bf16.h>

typedef __attribute__((ext_vector_type(4))) float  f32x4;
typedef __attribute__((ext_vector_type(4))) float  float4v;
typedef __attribute__((ext_vector_type(8))) short  bf16x8;
typedef __attribute__((ext_vector_type(4))) short  bf16x4;

#define LDT     72      // padded LDS row stride (bf16 units) = 144 B
#define XSTR_B  65536   // 32*32*64
#define XSTR_H  2048    // 32*64
#define XSTR_W  64
#define WSTR_P  36864   // 576*64
#define OSTR_B  57600   // 30*30*64

__device__ __forceinline__ short f2bf(float f) {
  union { float f; unsigned u; } v; v.f = f;
  unsigned r = v.u + 0x7fffu + ((v.u >> 16) & 1u);  // RNE
  return (short)(r >> 16);
}

__global__ __launch_bounds__(256, 2)   // cap 256 VGPR: the depth-1 prefetch (32 fp32 regs) must NOT spill
void lc2d_kernel(const float* __restrict__ x, const float* __restrict__ wgt,
                 const float* __restrict__ bias, float* __restrict__ out) {
  __shared__ short Asm[64 * LDT];   // A[b][k]  (patches, bf16)
  __shared__ short Wsm[64 * LDT];   // W^T[o][k] (weights, bf16)

  // bijective XCD swizzle: nwg=900, 8 XCDs, q=112, rr=4
  int orig = blockIdx.x;
  int xcd  = orig & 7;
  int idx  = orig >> 3;
  int p = (xcd < 4 ? xcd * 113 : 4 * 113 + (xcd - 4) * 112) + idx;
  int r = p / 30;
  int c = p - r * 30;

  int tid  = threadIdx.x;
  int lane = tid & 63;
  int wid  = tid >> 6;
  int wr   = (wid >> 1) * 32;   // wave's batch-row offset
  int wc   = (wid & 1) * 32;    // wave's filter-col offset
  int l16  = lane & 15;
  int lhi  = lane >> 4;

  // A staging coords: thread owns float4 at (row = it*16 + tid>>4, k = ac4..ac4+3)
  int ac4   = (tid & 15) * 4;
  int arow0 = tid >> 4;

  const float* xbase = x + (r * XSTR_H + c * XSTR_W);
  const float* wbase = wgt + p * WSTR_P;

  float4v av[4];
  float   wv[16];

  f32x4 acc[2][2] = {{{0.f,0.f,0.f,0.f},{0.f,0.f,0.f,0.f}},
                     {{0.f,0.f,0.f,0.f},{0.f,0.f,0.f,0.f}}};

  // chunk t covers f = t*64 .. t*64+63 ; di = t/3, dj = t%3 (compile-time after unroll)
  auto issue_loads = [&](int t) {
    int di = t / 3, dj = t - di * 3;
    const float* xa = xbase + di * XSTR_H + dj * XSTR_W + ac4;
#pragma unroll
    for (int it = 0; it < 4; ++it) {
      int b = it * 16 + arow0;
      av[it] = *(const float4v*)(xa + (long)b * XSTR_B);   // x: temporal (9x tap reuse via L2/L3)
    }
    // W: use-once stream -> non-temporal (don't thrash L2/L3, don't evict dirty harness lines)
    const float* wa = wbase + (t * 64 + wid * 16) * 64 + lane;
#pragma unroll
    for (int i = 0; i < 16; ++i) wv[i] = __builtin_nontemporal_load(wa + i * 64);
  };

  issue_loads(0);

#pragma unroll
  for (int t = 0; t < 9; ++t) {
    __syncthreads();                 // previous chunk's LDS reads done
    // ---- stage A: bf16x4 writes, row b, cols ac4..ac4+3
#pragma unroll
    for (int it = 0; it < 4; ++it) {
      int b = it * 16 + arow0;
      bf16x4 w4 = { f2bf(av[it].x), f2bf(av[it].y), f2bf(av[it].z), f2bf(av[it].w) };
      *(bf16x4*)&Asm[b * LDT + ac4] = w4;
    }
    // ---- stage W transposed: lane holds W[f = t*64+wid*16+i][o = lane] -> Wsm[o][k]
    {
      bf16x8 lo, hi;
#pragma unroll
      for (int i = 0; i < 8; ++i) { lo[i] = f2bf(wv[i]); hi[i] = f2bf(wv[8 + i]); }
      *(bf16x8*)&Wsm[lane * LDT + wid * 16]     = lo;
      *(bf16x8*)&Wsm[lane * LDT + wid * 16 + 8] = hi;
    }
    if (t < 8) issue_loads(t + 1);   // prefetch t+1: regs consumed by the ds_writes above; start loads before the barrier
    __syncthreads();
    // ---- compute: 2 k-steps of 32, 2x2 fragments
#pragma unroll
    for (int s = 0; s < 2; ++s) {
      int kb = s * 32 + lhi * 8;
      bf16x8 a0 = *(const bf16x8*)&Asm[(wr +  0 + l16) * LDT + kb];
      bf16x8 a1 = *(const bf16x8*)&Asm[(wr + 16 + l16) * LDT + kb];
      bf16x8 b0 = *(const bf16x8*)&Wsm[(wc +  0 + l16) * LDT + kb];
      bf16x8 b1 = *(const bf16x8*)&Wsm[(wc + 16 + l16) * LDT + kb];
      acc[0][0] = __builtin_amdgcn_mfma_f32_16x16x32_bf16(a0, b0, acc[0][0], 0, 0, 0);
      acc[0][1] = __builtin_amdgcn_mfma_f32_16x16x32_bf16(a0, b1, acc[0][1], 0, 0, 0);
      acc[1][0] = __builtin_amdgcn_mfma_f32_16x16x32_bf16(a1, b0, acc[1][0], 0, 0, 0);
      acc[1][1] = __builtin_amdgcn_mfma_f32_16x16x32_bf16(a1, b1, acc[1][1], 0, 0, 0);
    }
  }

  // ---- epilogue: bias + relu + NT store (D layout: col = lane&15, row = (lane>>4)*4 + reg)
  const float* bb = bias + (r * 30 + c) * 64;
  float bv0 = bb[wc + l16];
  float bv1 = bb[wc + 16 + l16];
  float* ob = out + (r * 30 + c) * 64;
#pragma unroll
  for (int m = 0; m < 2; ++m) {
#pragma unroll
    for (int j = 0; j < 4; ++j) {
      int b = wr + m * 16 + lhi * 4 + j;
#pragma unroll
      for (int n = 0; n < 2; ++n) {
        float v = acc[m][n][j] + (n ? bv1 : bv0);
        __builtin_nontemporal_store(fmaxf(v, 0.f), &ob[(long)b * OSTR_B + wc + n * 16 + l16]);
      }
    }
  }
}

extern "C" void kernel_launch(void* const* d_in, const int* in_sizes, int n_in,
                              void* d_out, int out_size, void* d_ws, size_t ws_size,
                              hipStream_t stream) {
  const float* x    = (const float*)d_in[0];
  const float* wgt  = (const float*)d_in[1];
  const float* bias = (const float*)d_in[2];
  float* out = (float*)d_out;
  hipLaunchKernelGGL(lc2d_kernel, dim3(900), dim3(256), 0, stream, x, wgt, bias, out);
}